// Round 4
// baseline (314.370 us; speedup 1.0000x reference)
//
#include <hip/hip_runtime.h>

#define KSIZE 7
#define SR    2
#define NBINS (KSIZE * KSIZE)
#define NMAX  4096
#define BMAX  8

typedef float v4f __attribute__((ext_vector_type(4)));

// Problem-fixed geometry (asserted by launcher): H=W=64, C=256.
constexpr int C4c  = 64;     // C/4   (v4f units per pixel)
constexpr int WC4c = 4096;   // W*C4  (v4f units per row)

// ---------------------------------------------------------------------------
// One-block bucketing: builds assign[bb] = roi index, such that bb % B ==
// batch of that roi wherever possible (blocks round-robin across the 8 XCDs,
// so bucket k lands on XCD k -> per-XCD L2 holds exactly one image).
// ---------------------------------------------------------------------------
__global__ __launch_bounds__(256) void bucket_kernel(
    const int* __restrict__ bi, int* __restrict__ assign, int N, int B, int cap)
{
    __shared__ int cnt[BMAX];
    __shared__ int ovf_n, ovf_c;
    __shared__ int asg[NMAX];
    __shared__ int ovf[NMAX];

    const int t = threadIdx.x;
    if (t < BMAX) cnt[t] = 0;
    if (t == 0) { ovf_n = 0; ovf_c = 0; }
    for (int i = t; i < N; i += 256) asg[i] = -1;
    __syncthreads();

    for (int i = t; i < N; i += 256) {
        int k = bi[i];
        int p = atomicAdd(&cnt[k], 1);           // LDS atomic: cheap
        if (p < cap) asg[p * B + k] = i;         // primary slot on XCD k
        else { int q = atomicAdd(&ovf_n, 1); ovf[q] = i; }
    }
    __syncthreads();

    for (int i = t; i < N; i += 256) {           // fill holes from overflow
        if (asg[i] < 0) { int q = atomicAdd(&ovf_c, 1); asg[i] = ovf[q]; }
    }
    __syncthreads();

    for (int i = t; i < N; i += 256) assign[i] = asg[i];
}

// ---------------------------------------------------------------------------
// Shared tables for the merged per-axis slots (written once per block).
// slot layout per bin-row/bin-col: 4 indices + 4 weights; duplicates repeat
// an earlier index with weight 0 (branchless loads, L1/MSHR-merged).
// ---------------------------------------------------------------------------
__global__ __launch_bounds__(256, 3) void roialign_kernel(
    const float* __restrict__ x,         // [B,H,W,C]
    const float* __restrict__ rois,      // [N,4] (y1,x1,y2,x2)
    const int*   __restrict__ batch_idx, // [N]
    float*       __restrict__ out,       // [N,K,K,C]
    const int*   __restrict__ assign,
    int H, int W, int C)
{
    __shared__ int   sh_n;
    __shared__ int   ridx[KSIZE][4];
    __shared__ float rwgt[KSIZE][4];
    __shared__ int   cidx[KSIZE][4];
    __shared__ float cwgt[KSIZE][4];

    const int t = threadIdx.x;
    if (t == 0) sh_n = assign[blockIdx.x];
    __syncthreads();
    const int n = sh_n;

    const float4 rb = ((const float4*)rois)[n];   // (y1,x1,y2,x2) broadcast
    const float bin_h = (rb.z - rb.x) / (float)KSIZE;
    const float bin_w = (rb.w - rb.y) / (float)KSIZE;

    // Per-axis merge: threads 0..6 do rows, 16..22 do cols. Samples for bin k
    // sit at (k+0.25) and (k+0.75) bin-units; their bilinear neighbor sets
    // collapse to 2..4 unique indices. 0.5 folded per axis (0.25 total).
    if (t < KSIZE || (t >= 16 && t < 16 + KSIZE)) {
        const bool isrow = (t < KSIZE);
        const int  k     = isrow ? t : t - 16;
        const float base = isrow ? rb.x : rb.y;
        const float bsz  = isrow ? bin_h : bin_w;
        const int   dim  = isrow ? H : W;

        const float sA = base + ((float)k + 0.25f) * bsz;
        const float sB = base + ((float)k + 0.75f) * bsz;
        const float fA = fminf(fmaxf(floorf(sA), 0.0f), (float)(dim - 2));
        const float fB = fminf(fmaxf(floorf(sB), 0.0f), (float)(dim - 2));
        const int   iA = (int)fA,  iB = (int)fB;
        const float lA = fminf(fmaxf(sA - fA, 0.0f), 1.0f);
        const float lB = fminf(fmaxf(sB - fB, 0.0f), 1.0f);

        int   i0 = iA,     i1 = iA + 1, i2, i3;
        float w0 = (1.0f - lA) * 0.5f, w1 = lA * 0.5f, w2, w3;
        if (iB == iA) {                 // full overlap: 2 unique
            w0 += (1.0f - lB) * 0.5f;
            w1 += lB * 0.5f;
            i2 = iA; w2 = 0.0f;
            i3 = iA; w3 = 0.0f;
        } else if (iB == iA + 1) {      // shares one: 3 unique
            w1 += (1.0f - lB) * 0.5f;
            i2 = iB + 1; w2 = lB * 0.5f;
            i3 = iA;     w3 = 0.0f;
        } else {                        // disjoint: 4 unique
            i2 = iB;     w2 = (1.0f - lB) * 0.5f;
            i3 = iB + 1; w3 = lB * 0.5f;
        }
        if (isrow) {
            ridx[k][0] = i0; ridx[k][1] = i1; ridx[k][2] = i2; ridx[k][3] = i3;
            rwgt[k][0] = w0; rwgt[k][1] = w1; rwgt[k][2] = w2; rwgt[k][3] = w3;
        } else {
            cidx[k][0] = i0; cidx[k][1] = i1; cidx[k][2] = i2; cidx[k][3] = i3;
            cwgt[k][0] = w0; cwgt[k][1] = w1; cwgt[k][2] = w2; cwgt[k][3] = w3;
        }
    }
    __syncthreads();

    const int bimg = batch_idx[n];
    const int lane = t & 63;
    const int wave = t >> 6;

    const v4f* __restrict__ xbase =
        (const v4f*)x + (size_t)bimg * 64 * WC4c + lane;
    float* __restrict__ outn = out + (size_t)n * NBINS * 256;

    // 2-deep pipeline, ping-pong register sets (static names, no runtime idx).
    v4f vA[16], vB[16];

#define ISSUE(V, KY, KX)                                                    \
    do {                                                                    \
        const v4f* r0_ = xbase + ridx[KY][0] * WC4c;                        \
        const v4f* r1_ = xbase + ridx[KY][1] * WC4c;                        \
        const v4f* r2_ = xbase + ridx[KY][2] * WC4c;                        \
        const v4f* r3_ = xbase + ridx[KY][3] * WC4c;                        \
        const int c0_ = cidx[KX][0] * C4c, c1_ = cidx[KX][1] * C4c;         \
        const int c2_ = cidx[KX][2] * C4c, c3_ = cidx[KX][3] * C4c;         \
        V[0]  = r0_[c0_]; V[1]  = r0_[c1_]; V[2]  = r0_[c2_]; V[3]  = r0_[c3_]; \
        V[4]  = r1_[c0_]; V[5]  = r1_[c1_]; V[6]  = r1_[c2_]; V[7]  = r1_[c3_]; \
        V[8]  = r2_[c0_]; V[9]  = r2_[c1_]; V[10] = r2_[c2_]; V[11] = r2_[c3_]; \
        V[12] = r3_[c0_]; V[13] = r3_[c1_]; V[14] = r3_[c2_]; V[15] = r3_[c3_]; \
    } while (0)

#define COMPUTE(V, BIN, KY, KX)                                             \
    do {                                                                    \
        v4f acc = {0.f, 0.f, 0.f, 0.f};                                     \
        _Pragma("unroll")                                                   \
        for (int r_ = 0; r_ < 4; ++r_) {                                    \
            const float wr_ = rwgt[KY][r_];                                 \
            acc += V[r_*4+0] * (wr_ * cwgt[KX][0]);                         \
            acc += V[r_*4+1] * (wr_ * cwgt[KX][1]);                         \
            acc += V[r_*4+2] * (wr_ * cwgt[KX][2]);                         \
            acc += V[r_*4+3] * (wr_ * cwgt[KX][3]);                         \
        }                                                                   \
        v4f* op_ = (v4f*)(outn + (size_t)(BIN) * 256) + lane;               \
        __builtin_nontemporal_store(acc, op_);                              \
    } while (0)

    int bin = wave;                 // wave < 4 <= NBINS, so always valid
    int kyA = bin / KSIZE, kxA = bin - kyA * KSIZE;
    int kyB, kxB;
    ISSUE(vA, kyA, kxA);
    for (;;) {
        int nb = bin + 4;
        if (nb < NBINS) {
            kyB = nb / KSIZE; kxB = nb - kyB * KSIZE;
            ISSUE(vB, kyB, kxB);                      // prefetch next
            COMPUTE(vA, bin, kyA, kxA);
            bin = nb;
        } else {
            COMPUTE(vA, bin, kyA, kxA);
            break;
        }
        nb = bin + 4;
        if (nb < NBINS) {
            kyA = nb / KSIZE; kxA = nb - kyA * KSIZE;
            ISSUE(vA, kyA, kxA);                      // prefetch next
            COMPUTE(vB, bin, kyB, kxB);
            bin = nb;
        } else {
            COMPUTE(vB, bin, kyB, kxB);
            break;
        }
    }
#undef ISSUE
#undef COMPUTE
}

extern "C" void kernel_launch(void* const* d_in, const int* in_sizes, int n_in,
                              void* d_out, int out_size, void* d_ws, size_t ws_size,
                              hipStream_t stream) {
    const float* x         = (const float*)d_in[0];
    const float* rois      = (const float*)d_in[1];
    const int*   batch_idx = (const int*)d_in[2];
    float*       out       = (float*)d_out;
    int*         assign    = (int*)d_ws;

    const int H = 64, W = 64, C = 256;
    const int N = in_sizes[1] / 4;                 // rois is [N,4]
    const int B = in_sizes[0] / (H * W * C);       // 8
    const int cap = N / B;                         // 512

    bucket_kernel<<<1, 256, 0, stream>>>(batch_idx, assign, N, B, cap);
    roialign_kernel<<<N, 256, 0, stream>>>(x, rois, batch_idx, out, assign,
                                           H, W, C);
}

// Round 5
// 297.833 us; speedup vs baseline: 1.0555x; 1.0555x over previous
//
#include <hip/hip_runtime.h>

#define KSIZE 7
#define SR    2
#define NBINS (KSIZE * KSIZE)
#define NMAX  4096
#define BMAX  8

typedef float v4f __attribute__((ext_vector_type(4)));

// Problem-fixed geometry (asserted by launcher): H=W=64, C=256.
constexpr int C4c  = 64;     // C/4   (v4f units per pixel)
constexpr int WC4c = 4096;   // W*C4  (v4f units per row)

// ---------------------------------------------------------------------------
// One-block bucketing: builds assign[bb] = roi index, such that bb % B ==
// batch of that roi wherever possible (blocks round-robin across the 8 XCDs,
// so bucket k lands on XCD k -> per-XCD L2 holds exactly one image).
// ---------------------------------------------------------------------------
__global__ __launch_bounds__(256) void bucket_kernel(
    const int* __restrict__ bi, int* __restrict__ assign, int N, int B, int cap)
{
    __shared__ int cnt[BMAX];
    __shared__ int ovf_n, ovf_c;
    __shared__ int asg[NMAX];
    __shared__ int ovf[NMAX];

    const int t = threadIdx.x;
    if (t < BMAX) cnt[t] = 0;
    if (t == 0) { ovf_n = 0; ovf_c = 0; }
    for (int i = t; i < N; i += 256) asg[i] = -1;
    __syncthreads();

    for (int i = t; i < N; i += 256) {
        int k = bi[i];
        int p = atomicAdd(&cnt[k], 1);           // LDS atomic: cheap
        if (p < cap) asg[p * B + k] = i;         // primary slot on XCD k
        else { int q = atomicAdd(&ovf_n, 1); ovf[q] = i; }
    }
    __syncthreads();

    for (int i = t; i < N; i += 256) {           // fill holes from overflow
        if (asg[i] < 0) { int q = atomicAdd(&ovf_c, 1); asg[i] = ovf[q]; }
    }
    __syncthreads();

    for (int i = t; i < N; i += 256) assign[i] = asg[i];
}

// ---------------------------------------------------------------------------
// Main kernel. R4 post-mortem: dedup of unique BYTES didn't move time ->
// bound by per-CU load-instruction delivery (each 1024B wave-load costs
// ~25cyc regardless of cache residency). R5: issue only the nr x nc loads
// whose weights are nonzero (merge phase compacts slots: nonzero first).
// nr/nc are wave-uniform -> 9-way uniform switch, static unrolled bodies.
// Unloaded V slots hold stale-but-finite values killed by 0-weights in the
// (unchanged, VALU-cheap) 4x4 FMA.  E[loads/bin] ~= 10.8 vs 16.
// ---------------------------------------------------------------------------
__global__ __launch_bounds__(256, 3) void roialign_kernel(
    const float* __restrict__ x,         // [B,H,W,C]
    const float* __restrict__ rois,      // [N,4] (y1,x1,y2,x2)
    const int*   __restrict__ batch_idx, // [N]
    float*       __restrict__ out,       // [N,K,K,C]
    const int*   __restrict__ assign,
    int H, int W, int C)
{
    __shared__ int   sh_n;
    __shared__ int   ridx[KSIZE][4];
    __shared__ float rwgt[KSIZE][4];
    __shared__ int   cidx[KSIZE][4];
    __shared__ float cwgt[KSIZE][4];
    __shared__ int   rn[KSIZE];          // unique row-slot count (2..4)
    __shared__ int   cn[KSIZE];          // unique col-slot count (2..4)

    const int t = threadIdx.x;
    if (t == 0) sh_n = assign[blockIdx.x];
    __syncthreads();
    const int n = sh_n;

    const float4 rb = ((const float4*)rois)[n];   // (y1,x1,y2,x2) broadcast
    const float bin_h = (rb.z - rb.x) / (float)KSIZE;
    const float bin_w = (rb.w - rb.y) / (float)KSIZE;

    // Per-axis merge: threads 0..6 rows, 16..22 cols. Samples for bin k at
    // (k+0.25),(k+0.75) bin-units; neighbor sets collapse to 2..4 unique
    // indices, compacted nonzero-weight-first. 0.5 folded per axis.
    if (t < KSIZE || (t >= 16 && t < 16 + KSIZE)) {
        const bool isrow = (t < KSIZE);
        const int  k     = isrow ? t : t - 16;
        const float base = isrow ? rb.x : rb.y;
        const float bsz  = isrow ? bin_h : bin_w;
        const int   dim  = isrow ? H : W;

        const float sA = base + ((float)k + 0.25f) * bsz;
        const float sB = base + ((float)k + 0.75f) * bsz;
        const float fA = fminf(fmaxf(floorf(sA), 0.0f), (float)(dim - 2));
        const float fB = fminf(fmaxf(floorf(sB), 0.0f), (float)(dim - 2));
        const int   iA = (int)fA,  iB = (int)fB;
        const float lA = fminf(fmaxf(sA - fA, 0.0f), 1.0f);
        const float lB = fminf(fmaxf(sB - fB, 0.0f), 1.0f);

        int   i0 = iA,     i1 = iA + 1, i2, i3, cnt_;
        float w0 = (1.0f - lA) * 0.5f, w1 = lA * 0.5f, w2, w3;
        if (iB == iA) {                 // full overlap: 2 unique
            w0 += (1.0f - lB) * 0.5f;
            w1 += lB * 0.5f;
            i2 = iA; w2 = 0.0f;
            i3 = iA; w3 = 0.0f;
            cnt_ = 2;
        } else if (iB == iA + 1) {      // shares one: 3 unique
            w1 += (1.0f - lB) * 0.5f;
            i2 = iB + 1; w2 = lB * 0.5f;
            i3 = iA;     w3 = 0.0f;
            cnt_ = 3;
        } else {                        // disjoint: 4 unique
            i2 = iB;     w2 = (1.0f - lB) * 0.5f;
            i3 = iB + 1; w3 = lB * 0.5f;
            cnt_ = 4;
        }
        if (isrow) {
            ridx[k][0] = i0; ridx[k][1] = i1; ridx[k][2] = i2; ridx[k][3] = i3;
            rwgt[k][0] = w0; rwgt[k][1] = w1; rwgt[k][2] = w2; rwgt[k][3] = w3;
            rn[k] = cnt_;
        } else {
            cidx[k][0] = i0; cidx[k][1] = i1; cidx[k][2] = i2; cidx[k][3] = i3;
            cwgt[k][0] = w0; cwgt[k][1] = w1; cwgt[k][2] = w2; cwgt[k][3] = w3;
            cn[k] = cnt_;
        }
    }
    __syncthreads();

    const int bimg = batch_idx[n];
    const int lane = t & 63;
    const int wave = t >> 6;

    const v4f* __restrict__ xbase =
        (const v4f*)x + (size_t)bimg * 64 * WC4c + lane;
    float* __restrict__ outn = out + (size_t)n * NBINS * 256;

    // 2-deep pipeline, ping-pong register sets (static names, no runtime idx).
    // Zero-init so never-loaded slots are finite (0 * 0-weight == 0).
    v4f vA[16], vB[16];
    #pragma unroll
    for (int i = 0; i < 16; ++i) {
        vA[i] = (v4f){0.f, 0.f, 0.f, 0.f};
        vB[i] = (v4f){0.f, 0.f, 0.f, 0.f};
    }

// -- load-row helpers: LR<nc>(slot-row, row-ptr) -----------------------------
#define LR2(RV, RP) V[(RV)*4+0] = (RP)[c0_]; V[(RV)*4+1] = (RP)[c1_];
#define LR3(RV, RP) LR2(RV, RP) V[(RV)*4+2] = (RP)[c2_];
#define LR4(RV, RP) LR3(RV, RP) V[(RV)*4+3] = (RP)[c3_];
#define LDN2(NC) LR##NC(0, r0_) LR##NC(1, r1_)
#define LDN3(NC) LDN2(NC) LR##NC(2, r2_)
#define LDN4(NC) LDN3(NC) LR##NC(3, r3_)

#define ISSUE(VARR, KY, KX)                                                 \
    do {                                                                    \
        v4f (&V)[16] = VARR;                                                \
        const v4f* r0_ = xbase + ridx[KY][0] * WC4c;                        \
        const v4f* r1_ = xbase + ridx[KY][1] * WC4c;                        \
        const v4f* r2_ = xbase + ridx[KY][2] * WC4c;                        \
        const v4f* r3_ = xbase + ridx[KY][3] * WC4c;                        \
        const int c0_ = cidx[KX][0] * C4c, c1_ = cidx[KX][1] * C4c;         \
        const int c2_ = cidx[KX][2] * C4c, c3_ = cidx[KX][3] * C4c;         \
        const int code_ = (rn[KY] - 2) * 3 + (cn[KX] - 2);                  \
        switch (code_) {                                                    \
        case 0: { LDN2(2) } break;                                          \
        case 1: { LDN2(3) } break;                                          \
        case 2: { LDN2(4) } break;                                          \
        case 3: { LDN3(2) } break;                                          \
        case 4: { LDN3(3) } break;                                          \
        case 5: { LDN3(4) } break;                                          \
        case 6: { LDN4(2) } break;                                          \
        case 7: { LDN4(3) } break;                                          \
        default: { LDN4(4) } break;                                         \
        }                                                                   \
    } while (0)

#define COMPUTE(VARR, BIN, KY, KX)                                          \
    do {                                                                    \
        v4f (&V)[16] = VARR;                                                \
        v4f acc = {0.f, 0.f, 0.f, 0.f};                                     \
        _Pragma("unroll")                                                   \
        for (int r_ = 0; r_ < 4; ++r_) {                                    \
            const float wr_ = rwgt[KY][r_];                                 \
            acc += V[r_*4+0] * (wr_ * cwgt[KX][0]);                         \
            acc += V[r_*4+1] * (wr_ * cwgt[KX][1]);                         \
            acc += V[r_*4+2] * (wr_ * cwgt[KX][2]);                         \
            acc += V[r_*4+3] * (wr_ * cwgt[KX][3]);                         \
        }                                                                   \
        v4f* op_ = (v4f*)(outn + (size_t)(BIN) * 256) + lane;               \
        __builtin_nontemporal_store(acc, op_);                              \
    } while (0)

    int bin = wave;                 // wave < 4 <= NBINS, so always valid
    int kyA = bin / KSIZE, kxA = bin - kyA * KSIZE;
    int kyB, kxB;
    ISSUE(vA, kyA, kxA);
    for (;;) {
        int nb = bin + 4;
        if (nb < NBINS) {
            kyB = nb / KSIZE; kxB = nb - kyB * KSIZE;
            ISSUE(vB, kyB, kxB);                      // prefetch next
            COMPUTE(vA, bin, kyA, kxA);
            bin = nb;
        } else {
            COMPUTE(vA, bin, kyA, kxA);
            break;
        }
        nb = bin + 4;
        if (nb < NBINS) {
            kyA = nb / KSIZE; kxA = nb - kyA * KSIZE;
            ISSUE(vA, kyA, kxA);                      // prefetch next
            COMPUTE(vB, bin, kyB, kxB);
            bin = nb;
        } else {
            COMPUTE(vB, bin, kyB, kxB);
            break;
        }
    }
#undef ISSUE
#undef COMPUTE
#undef LR2
#undef LR3
#undef LR4
#undef LDN2
#undef LDN3
#undef LDN4
}

extern "C" void kernel_launch(void* const* d_in, const int* in_sizes, int n_in,
                              void* d_out, int out_size, void* d_ws, size_t ws_size,
                              hipStream_t stream) {
    const float* x         = (const float*)d_in[0];
    const float* rois      = (const float*)d_in[1];
    const int*   batch_idx = (const int*)d_in[2];
    float*       out       = (float*)d_out;
    int*         assign    = (int*)d_ws;

    const int H = 64, W = 64, C = 256;
    const int N = in_sizes[1] / 4;                 // rois is [N,4]
    const int B = in_sizes[0] / (H * W * C);       // 8
    const int cap = N / B;                         // 512

    bucket_kernel<<<1, 256, 0, stream>>>(batch_idx, assign, N, B, cap);
    roialign_kernel<<<N, 256, 0, stream>>>(x, rois, batch_idx, out, assign,
                                           H, W, C);
}